// Round 13
// baseline (92.430 us; speedup 1.0000x reference)
//
#include <hip/hip_runtime.h>
#include <hip/hip_bf16.h>
#include <stdint.h>

typedef __attribute__((ext_vector_type(8))) short bf16x8;
typedef __attribute__((ext_vector_type(4))) float f32x4;

__device__ __forceinline__ short f2bf(float x) {
    __hip_bfloat16 h = __float2bfloat16(x);   // native cvt on gfx950 (RNE)
    return __builtin_bit_cast(short, h);
}

__device__ __forceinline__ bf16x8 pack8(f32x4 a, f32x4 b) {
    bf16x8 r;
    r[0] = f2bf(a[0]); r[1] = f2bf(a[1]); r[2] = f2bf(a[2]); r[3] = f2bf(a[3]);
    r[4] = f2bf(b[0]); r[5] = f2bf(b[1]); r[6] = f2bf(b[2]); r[7] = f2bf(b[3]);
    return r;
}

// ---------------------------------------------------------------------------
// Kernel C: repack Wq (1024x48 f32) into bf16 B-fragment layout.
// ---------------------------------------------------------------------------
__global__ __launch_bounds__(256) void prep_wfrag(const float* __restrict__ Wq,
                                                  short* __restrict__ wfrag) {
    int idx = blockIdx.x * 256 + threadIdx.x;   // 0..49151
    int j    = idx & 7;
    int lane = (idx >> 3) & 63;
    int grp  = idx >> 9;          // ks*3+nf
    int nf   = grp % 3;
    int ks   = grp / 3;
    int k = ks * 32 + ((lane >> 4) << 3) + j;
    int n = nf * 16 + (lane & 15);
    wfrag[idx] = f2bf(Wq[k * 48 + n]);
}

// ---------------------------------------------------------------------------
// Kernel A: qk = Q @ Wq + bq  (M=32768, N=48, K=1024), MFMA 16x16x32 bf16.
// Epilogue scatter-stores bf16 weights into A-frag layout:
//   wgtA[b][k][dg(128)][h(16)][8]
// ---------------------------------------------------------------------------
__global__ __launch_bounds__(256) void qk_gemm(const float* __restrict__ Q,
                                               const short* __restrict__ wfrag,
                                               const float* __restrict__ bq,
                                               short* __restrict__ wgtA) {
    const int l  = threadIdx.x & 63;
    const int w  = threadIdx.x >> 6;
    const int lr = l & 15;
    const int lk = l >> 4;
    const int row0 = blockIdx.x * 64 + w * 16;

    f32x4 acc[3];
    acc[0] = (f32x4){0.f, 0.f, 0.f, 0.f};
    acc[1] = acc[0];
    acc[2] = acc[0];

    const float* qbase = Q + (size_t)(row0 + lr) * 1024 + lk * 8;

    #pragma unroll 4
    for (int ks = 0; ks < 32; ++ks) {
        const float* p = qbase + ks * 32;
        f32x4 q0 = *(const f32x4*)p;
        f32x4 q1 = *(const f32x4*)(p + 4);
        bf16x8 a = pack8(q0, q1);
        const bf16x8* wp = (const bf16x8*)(wfrag + (size_t)ks * 1536 + l * 8);
        acc[0] = __builtin_amdgcn_mfma_f32_16x16x32_bf16(a, wp[0],   acc[0], 0, 0, 0);
        acc[1] = __builtin_amdgcn_mfma_f32_16x16x32_bf16(a, wp[64],  acc[1], 0, 0, 0);
        acc[2] = __builtin_amdgcn_mfma_f32_16x16x32_bf16(a, wp[128], acc[2], 0, 0, 0);
    }

    #pragma unroll
    for (int nf = 0; nf < 3; ++nf) {
        int n = nf * 16 + lr;
        float bias = bq[n];
        int t  = n / 3;
        int kk = n - t * 3;
        #pragma unroll
        for (int r = 0; r < 4; ++r) {
            int row = row0 + lk * 4 + r;
            int b   = row >> 10;
            int h   = (row >> 6) & 15;
            int sp  = row & 63;
            int dg  = sp * 2 + (t >> 3);
            int j   = t & 7;
            wgtA[(((size_t)(b * 3 + kk) * 128 + dg) << 7) + h * 8 + j] = f2bf(acc[nf][r] + bias);
        }
    }
}

// ---------------------------------------------------------------------------
// Kernel B v13: qk-CLONE conv. No LDS staging, no barriers, no asm, no
// selects in the loop. Each lane: 3 marching key streams (taps s-1,s,s+1,
// 32B/iter each) + 1 contiguous wgt stream, feeding pack8 -> MFMA exactly
// like qk_gemm's proven 7 TB/s body. Boundary rows (-1, 1024) eliminated by
// pointing those lanes' tap streams at a zeroed 4KB scratch page -> loop
// body is unconditional pure loads for ALL lanes.
// Grid 1024 (32b x 32st) XCD-swizzled, 256 thr: ss=w&1 (16 s), dh=w>>1
// (512-d half), 16 iters x 32 d. d-halves combined via tiny LDS reduce.
// ---------------------------------------------------------------------------
__global__ __launch_bounds__(256, 4) void conv_mfma(const float* __restrict__ Key,
                                                    const short* __restrict__ wgtA,
                                                    const float* __restrict__ zpage,
                                                    float* __restrict__ out) {
    __shared__ float red[2][16][17];
    const int blk = (blockIdx.x & 7) * 128 + (blockIdx.x >> 3);  // XCD swizzle
    const int st  = blk & 31;
    const int b   = blk >> 5;
    const int tid = threadIdx.x;
    const int l   = tid & 63;
    const int w   = tid >> 6;
    const int lr  = l & 15;
    const int lk  = l >> 4;
    const int ss  = w & 1;
    const int dh  = w >> 1;
    const int s   = (st << 5) + (ss << 4) + lr;

    const float* keyB = Key + ((size_t)b << 20) + (dh << 9) + (lk << 3);
    const float* zp   = zpage + (lk << 3);
    const f32x4* pk0 = (const f32x4*)((s == 0)    ? zp : keyB + (size_t)(s - 1) * 1024);
    const f32x4* pk1 = (const f32x4*)(keyB + (size_t)s * 1024);
    const f32x4* pk2 = (const f32x4*)((s == 1023) ? zp : keyB + (size_t)(s + 1) * 1024);
    const short* wgtW = wgtA + (((size_t)b * 384 + (dh << 6) + lk) << 7) + lr * 8;

    f32x4 acc = (f32x4){0.f, 0.f, 0.f, 0.f};

    #pragma unroll 4
    for (int t = 0; t < 16; ++t) {
        f32x4 k00 = pk0[t * 8], k01 = pk0[t * 8 + 1];
        f32x4 k10 = pk1[t * 8], k11 = pk1[t * 8 + 1];
        f32x4 k20 = pk2[t * 8], k21 = pk2[t * 8 + 1];
        const bf16x8* wp = (const bf16x8*)(wgtW + t * 512);
        bf16x8 a0 = wp[0];
        bf16x8 a1 = *(const bf16x8*)(wgtW + 16384 + t * 512);
        bf16x8 a2 = *(const bf16x8*)(wgtW + 32768 + t * 512);
        acc = __builtin_amdgcn_mfma_f32_16x16x32_bf16(a0, pack8(k00, k01), acc, 0, 0, 0);
        acc = __builtin_amdgcn_mfma_f32_16x16x32_bf16(a1, pack8(k10, k11), acc, 0, 0, 0);
        acc = __builtin_amdgcn_mfma_f32_16x16x32_bf16(a2, pack8(k20, k21), acc, 0, 0, 0);
    }

    // combine d-halves (single barrier in whole kernel)
    if (dh == 1) {
        #pragma unroll
        for (int r4 = 0; r4 < 4; ++r4) red[ss][lk * 4 + r4][lr] = acc[r4];
    }
    __syncthreads();
    if (dh == 0) {
        #pragma unroll
        for (int r4 = 0; r4 < 4; ++r4) {
            int h = lk * 4 + r4;
            out[(((b << 4) + h) << 10) + s] = acc[r4] + red[ss][h][lr];
        }
    }
}

extern "C" void kernel_launch(void* const* d_in, const int* in_sizes, int n_in,
                              void* d_out, int out_size, void* d_ws, size_t ws_size,
                              hipStream_t stream) {
    const float* Q  = (const float*)d_in[0];
    const float* K  = (const float*)d_in[1];
    const float* Wq = (const float*)d_in[4];
    const float* bq = (const float*)d_in[5];
    float* outp = (float*)d_out;

    short* wfrag = (short*)d_ws;                              // 98304 B
    short* wgtA  = (short*)((char*)d_ws + 98304);             // 3145728 B
    float* zpage = (float*)((char*)d_ws + 98304 + 3145728);   // 4096 B zeros

    hipMemsetAsync(zpage, 0, 4096, stream);
    hipLaunchKernelGGL(prep_wfrag, dim3(192),  dim3(256), 0, stream, Wq, wfrag);
    hipLaunchKernelGGL(qk_gemm,    dim3(512),  dim3(256), 0, stream, Q, wfrag, bq, wgtA);
    hipLaunchKernelGGL(conv_mfma,  dim3(1024), dim3(256), 0, stream, K, wgtA, zpage, outp);
}

// Round 14
// 90.342 us; speedup vs baseline: 1.0231x; 1.0231x over previous
//
#include <hip/hip_runtime.h>
#include <hip/hip_bf16.h>
#include <stdint.h>

typedef __attribute__((ext_vector_type(8))) short bf16x8;
typedef __attribute__((ext_vector_type(4))) float f32x4;

__device__ __forceinline__ short f2bf(float x) {
    __hip_bfloat16 h = __float2bfloat16(x);   // native cvt on gfx950 (RNE)
    return __builtin_bit_cast(short, h);
}

__device__ __forceinline__ bf16x8 pack8(f32x4 a, f32x4 b) {
    bf16x8 r;
    r[0] = f2bf(a[0]); r[1] = f2bf(a[1]); r[2] = f2bf(a[2]); r[3] = f2bf(a[3]);
    r[4] = f2bf(b[0]); r[5] = f2bf(b[1]); r[6] = f2bf(b[2]); r[7] = f2bf(b[3]);
    return r;
}

// ---------------------------------------------------------------------------
// Kernel C: repack Wq (1024x48 f32) into bf16 B-fragment layout.
// ---------------------------------------------------------------------------
__global__ __launch_bounds__(256) void prep_wfrag(const float* __restrict__ Wq,
                                                  short* __restrict__ wfrag) {
    int idx = blockIdx.x * 256 + threadIdx.x;   // 0..49151
    int j    = idx & 7;
    int lane = (idx >> 3) & 63;
    int grp  = idx >> 9;          // ks*3+nf
    int nf   = grp % 3;
    int ks   = grp / 3;
    int k = ks * 32 + ((lane >> 4) << 3) + j;
    int n = nf * 16 + (lane & 15);
    wfrag[idx] = f2bf(Wq[k * 48 + n]);
}

// ---------------------------------------------------------------------------
// Kernel A: qk = Q @ Wq + bq  (M=32768, N=48, K=1024), MFMA 16x16x32 bf16.
// Epilogue scatter-stores bf16 weights into A-frag layout:
//   wgtA[b][k][dg(128)][h(16)][8]
// ---------------------------------------------------------------------------
__global__ __launch_bounds__(256) void qk_gemm(const float* __restrict__ Q,
                                               const short* __restrict__ wfrag,
                                               const float* __restrict__ bq,
                                               short* __restrict__ wgtA) {
    const int l  = threadIdx.x & 63;
    const int w  = threadIdx.x >> 6;
    const int lr = l & 15;
    const int lk = l >> 4;
    const int row0 = blockIdx.x * 64 + w * 16;

    f32x4 acc[3];
    acc[0] = (f32x4){0.f, 0.f, 0.f, 0.f};
    acc[1] = acc[0];
    acc[2] = acc[0];

    const float* qbase = Q + (size_t)(row0 + lr) * 1024 + lk * 8;

    #pragma unroll 4
    for (int ks = 0; ks < 32; ++ks) {
        const float* p = qbase + ks * 32;
        f32x4 q0 = *(const f32x4*)p;
        f32x4 q1 = *(const f32x4*)(p + 4);
        bf16x8 a = pack8(q0, q1);
        const bf16x8* wp = (const bf16x8*)(wfrag + (size_t)ks * 1536 + l * 8);
        acc[0] = __builtin_amdgcn_mfma_f32_16x16x32_bf16(a, wp[0],   acc[0], 0, 0, 0);
        acc[1] = __builtin_amdgcn_mfma_f32_16x16x32_bf16(a, wp[64],  acc[1], 0, 0, 0);
        acc[2] = __builtin_amdgcn_mfma_f32_16x16x32_bf16(a, wp[128], acc[2], 0, 0, 0);
    }

    #pragma unroll
    for (int nf = 0; nf < 3; ++nf) {
        int n = nf * 16 + lr;
        float bias = bq[n];
        int t  = n / 3;
        int kk = n - t * 3;
        #pragma unroll
        for (int r = 0; r < 4; ++r) {
            int row = row0 + lk * 4 + r;
            int b   = row >> 10;
            int h   = (row >> 6) & 15;
            int sp  = row & 63;
            int dg  = sp * 2 + (t >> 3);
            int j   = t & 7;
            wgtA[(((size_t)(b * 3 + kk) * 128 + dg) << 7) + h * 8 + j] = f2bf(acc[nf][r] + bias);
        }
    }
}

// ---------------------------------------------------------------------------
// Kernel B v15: direct-load conv in qk's EXACT regime.
//  - grid 512 (32b x 16st, XCD swizzle), 4 waves/block, 8 waves/CU (= qk)
//  - each wave: independent 16h x 16s tile, FULL K'=3072 (32 iters x 32d),
//    no d-split -> no reduction, NO LDS, NO barriers
//  - plain __launch_bounds__(256): VGPR free (no forced load-sinking)
//  - L1 working set: 2 blocks/CU x 66 rows x 128B = 16.5KB < 32KB L1 ->
//    3x tap reuse hits L1 (v13's 36KB thrashed it)
//  - zpage boundary elimination: no selects in loop body
// ---------------------------------------------------------------------------
__global__ __launch_bounds__(256) void conv_mfma(const float* __restrict__ Key,
                                                 const short* __restrict__ wgtA,
                                                 const float* __restrict__ zpage,
                                                 float* __restrict__ out) {
    const int blk = (blockIdx.x & 7) * 64 + (blockIdx.x >> 3);  // bijective XCD swizzle (512%8==0)
    const int st  = blk & 15;
    const int b   = blk >> 4;
    const int tid = threadIdx.x;
    const int l   = tid & 63;
    const int w   = tid >> 6;          // s-subtile 0..3
    const int lr  = l & 15;
    const int lk  = l >> 4;
    const int s   = (st << 6) + (w << 4) + lr;

    const float* keyB = Key + ((size_t)b << 20) + (lk << 3);
    const float* zp   = zpage + (lk << 3);
    const f32x4* pk0 = (const f32x4*)((s == 0)    ? zp : keyB + (size_t)(s - 1) * 1024);
    const f32x4* pk1 = (const f32x4*)(keyB + (size_t)s * 1024);
    const f32x4* pk2 = (const f32x4*)((s == 1023) ? zp : keyB + (size_t)(s + 1) * 1024);
    // wgtA[((b*3+k)*128 + dg)*128 + h*8 + j], dg = t*4 + lk
    const short* wgtW = wgtA + (((size_t)b * 384 + lk) << 7) + lr * 8;

    f32x4 acc = (f32x4){0.f, 0.f, 0.f, 0.f};

    #pragma unroll 4
    for (int t = 0; t < 32; ++t) {
        f32x4 k00 = pk0[t * 8], k01 = pk0[t * 8 + 1];
        f32x4 k10 = pk1[t * 8], k11 = pk1[t * 8 + 1];
        f32x4 k20 = pk2[t * 8], k21 = pk2[t * 8 + 1];
        bf16x8 a0 = *(const bf16x8*)(wgtW +         t * 512);
        bf16x8 a1 = *(const bf16x8*)(wgtW + 16384 + t * 512);
        bf16x8 a2 = *(const bf16x8*)(wgtW + 32768 + t * 512);
        acc = __builtin_amdgcn_mfma_f32_16x16x32_bf16(a0, pack8(k00, k01), acc, 0, 0, 0);
        acc = __builtin_amdgcn_mfma_f32_16x16x32_bf16(a1, pack8(k10, k11), acc, 0, 0, 0);
        acc = __builtin_amdgcn_mfma_f32_16x16x32_bf16(a2, pack8(k20, k21), acc, 0, 0, 0);
    }

    // direct store: C frag row = h = lk*4+r, col = s
    #pragma unroll
    for (int r4 = 0; r4 < 4; ++r4) {
        int h = lk * 4 + r4;
        out[(((b << 4) + h) << 10) + s] = acc[r4];
    }
}

extern "C" void kernel_launch(void* const* d_in, const int* in_sizes, int n_in,
                              void* d_out, int out_size, void* d_ws, size_t ws_size,
                              hipStream_t stream) {
    const float* Q  = (const float*)d_in[0];
    const float* K  = (const float*)d_in[1];
    const float* Wq = (const float*)d_in[4];
    const float* bq = (const float*)d_in[5];
    float* outp = (float*)d_out;

    short* wfrag = (short*)d_ws;                              // 98304 B
    short* wgtA  = (short*)((char*)d_ws + 98304);             // 3145728 B
    float* zpage = (float*)((char*)d_ws + 98304 + 3145728);   // 4096 B zeros

    hipMemsetAsync(zpage, 0, 4096, stream);
    hipLaunchKernelGGL(prep_wfrag, dim3(192), dim3(256), 0, stream, Wq, wfrag);
    hipLaunchKernelGGL(qk_gemm,    dim3(512), dim3(256), 0, stream, Q, wfrag, bq, wgtA);
    hipLaunchKernelGGL(conv_mfma,  dim3(512), dim3(256), 0, stream, K, wgtA, zpage, outp);
}

// Round 15
// 66.684 us; speedup vs baseline: 1.3861x; 1.3548x over previous
//
#include <hip/hip_runtime.h>
#include <hip/hip_bf16.h>
#include <stdint.h>

typedef __attribute__((ext_vector_type(8))) short bf16x8;
typedef __attribute__((ext_vector_type(4))) float f32x4;

__device__ __forceinline__ short f2bf(float x) {
    __hip_bfloat16 h = __float2bfloat16(x);   // native cvt on gfx950 (RNE)
    return __builtin_bit_cast(short, h);
}

__device__ __forceinline__ bf16x8 pack8(f32x4 a, f32x4 b) {
    bf16x8 r;
    r[0] = f2bf(a[0]); r[1] = f2bf(a[1]); r[2] = f2bf(a[2]); r[3] = f2bf(a[3]);
    r[4] = f2bf(b[0]); r[5] = f2bf(b[1]); r[6] = f2bf(b[2]); r[7] = f2bf(b[3]);
    return r;
}

// ---------------------------------------------------------------------------
// Kernel C: repack Wq (1024x48 f32) into bf16 B-fragment layout.
// ---------------------------------------------------------------------------
__global__ __launch_bounds__(256) void prep_wfrag(const float* __restrict__ Wq,
                                                  short* __restrict__ wfrag) {
    int idx = blockIdx.x * 256 + threadIdx.x;   // 0..49151
    int j    = idx & 7;
    int lane = (idx >> 3) & 63;
    int grp  = idx >> 9;          // ks*3+nf
    int nf   = grp % 3;
    int ks   = grp / 3;
    int k = ks * 32 + ((lane >> 4) << 3) + j;
    int n = nf * 16 + (lane & 15);
    wfrag[idx] = f2bf(Wq[k * 48 + n]);
}

// ---------------------------------------------------------------------------
// Kernel A: qk = Q @ Wq + bq  (M=32768, N=48, K=1024), MFMA 16x16x32 bf16.
// Epilogue scatter-stores bf16 weights into A-frag-friendly layout:
//   wgtA[b][k][dg(128)][h(16)][8]  (dg = d>>3, j = d&7)
// ---------------------------------------------------------------------------
__global__ __launch_bounds__(256) void qk_gemm(const float* __restrict__ Q,
                                               const short* __restrict__ wfrag,
                                               const float* __restrict__ bq,
                                               short* __restrict__ wgtA) {
    const int l  = threadIdx.x & 63;
    const int w  = threadIdx.x >> 6;
    const int lr = l & 15;
    const int lk = l >> 4;
    const int row0 = blockIdx.x * 64 + w * 16;

    f32x4 acc[3];
    acc[0] = (f32x4){0.f, 0.f, 0.f, 0.f};
    acc[1] = acc[0];
    acc[2] = acc[0];

    const float* qbase = Q + (size_t)(row0 + lr) * 1024 + lk * 8;

    #pragma unroll 4
    for (int ks = 0; ks < 32; ++ks) {
        const float* p = qbase + ks * 32;
        f32x4 q0 = *(const f32x4*)p;
        f32x4 q1 = *(const f32x4*)(p + 4);
        bf16x8 a = pack8(q0, q1);
        const bf16x8* wp = (const bf16x8*)(wfrag + (size_t)ks * 1536 + l * 8);
        acc[0] = __builtin_amdgcn_mfma_f32_16x16x32_bf16(a, wp[0],   acc[0], 0, 0, 0);
        acc[1] = __builtin_amdgcn_mfma_f32_16x16x32_bf16(a, wp[64],  acc[1], 0, 0, 0);
        acc[2] = __builtin_amdgcn_mfma_f32_16x16x32_bf16(a, wp[128], acc[2], 0, 0, 0);
    }

    #pragma unroll
    for (int nf = 0; nf < 3; ++nf) {
        int n = nf * 16 + lr;
        float bias = bq[n];
        int t  = n / 3;
        int kk = n - t * 3;
        #pragma unroll
        for (int r = 0; r < 4; ++r) {
            int row = row0 + lk * 4 + r;
            int b   = row >> 10;
            int h   = (row >> 6) & 15;
            int sp  = row & 63;
            int dg  = sp * 2 + (t >> 3);
            int j   = t & 7;
            wgtA[(((size_t)(b * 3 + kk) * 128 + dg) << 7) + h * 8 + j] = f2bf(acc[nf][r] + bias);
        }
    }
}

// ---------------------------------------------------------------------------
// Kernel B v7 (PROVEN BEST, conv ~38.5 us): wave-private LDS pipelines, no
// loop barriers, A-fragment parity register prefetch one step ahead (issued
// before next key LOADS so MFMA waits never drain the key pipeline), XCD
// swizzle for L2-resident wgt, depth-1 key prefetch. (256,3).
// Grid 1024 blocks (32 b x 32 st), 256 thr; wave = 16h x 16s, d-half.
// ---------------------------------------------------------------------------
__global__ __launch_bounds__(256, 3) void conv_mfma(const float* __restrict__ Key,
                                                    const short* __restrict__ wgtA,
                                                    float* __restrict__ out) {
    __shared__ short klds[4][2][18][64];   // 4 waves x dbuf x 18 rows x 128B
    __shared__ float red[2][16][17];
    const int blk = (blockIdx.x & 7) * 128 + (blockIdx.x >> 3);  // bijective XCD swizzle
    const int st  = blk & 31;
    const int b   = blk >> 5;
    const int tid = threadIdx.x;
    const int l   = tid & 63;
    const int w   = tid >> 6;
    const int lr  = l & 15;
    const int lk  = l >> 4;
    const int ss  = w & 1;
    const int dh  = w >> 1;
    const int sbase = (st << 5) + (ss << 4);

    const int row16 = l >> 2;
    const int cg    = l & 3;
    const int rowX  = 16 + (l >> 2);        // meaningful for l<8
    const int srowA = sbase - 1 + row16;
    const int srowX = sbase + 15 + (l >> 2);
    const bool okA  = (srowA >= 0);
    const bool okX  = (l < 8) && (srowX < 1024);

    const float* keyW = Key + ((size_t)b << 20) + (dh << 9);
    const f32x4* pA = (const f32x4*)(keyW + (size_t)(okA ? srowA : 0) * 1024 + cg * 16);
    const f32x4* pX = (const f32x4*)(keyW + (size_t)(okX ? srowX : 0) * 1024 + cg * 16);

    char* ldsW = (char*)&klds[w][0][0][0];  // 4608B per wave, 2304B per buf
    const int swzA = (row16 & 7) << 4;
    const int swzX = (rowX & 7) << 4;

    const f32x4 z4 = (f32x4){0.f, 0.f, 0.f, 0.f};
    f32x4 mA[4], mX[4];

    #define LOADS(t) do {                                            \
        const int o = (t) * 16;                                      \
        mA[0] = okA ? pA[o]     : z4;  mA[1] = okA ? pA[o + 1] : z4; \
        mA[2] = okA ? pA[o + 2] : z4;  mA[3] = okA ? pA[o + 3] : z4; \
        mX[0] = okX ? pX[o]     : z4;  mX[1] = okX ? pX[o + 1] : z4; \
        mX[2] = okX ? pX[o + 2] : z4;  mX[3] = okX ? pX[o + 3] : z4; \
    } while (0)

    #define WRITES(buf) do {                                                  \
        char* bb = ldsW + (buf) * 2304;                                       \
        *(bf16x8*)(bb + row16 * 128 + (((cg << 5))      ^ swzA)) = pack8(mA[0], mA[1]); \
        *(bf16x8*)(bb + row16 * 128 + (((cg << 5) + 16) ^ swzA)) = pack8(mA[2], mA[3]); \
        if (l < 8) {                                                          \
            *(bf16x8*)(bb + rowX * 128 + (((cg << 5))      ^ swzX)) = pack8(mX[0], mX[1]); \
            *(bf16x8*)(bb + rowX * 128 + (((cg << 5) + 16) ^ swzX)) = pack8(mX[2], mX[3]); \
        }                                                                     \
    } while (0)

    const short* wgtW = wgtA + (((size_t)b * 384 + (dh << 6) + lk) << 7) + lr * 8;

    // A-fragment prefetch: arr[k*2+kk] for step tt
    #define ALOAD(arr, tt) do {                                               \
        arr[0] = *(const bf16x8*)(wgtW +         (tt) * 1024);                \
        arr[1] = *(const bf16x8*)(wgtW +         (tt) * 1024 + 512);          \
        arr[2] = *(const bf16x8*)(wgtW + 16384 + (tt) * 1024);                \
        arr[3] = *(const bf16x8*)(wgtW + 16384 + (tt) * 1024 + 512);          \
        arr[4] = *(const bf16x8*)(wgtW + 32768 + (tt) * 1024);                \
        arr[5] = *(const bf16x8*)(wgtW + 32768 + (tt) * 1024 + 512);          \
    } while (0)

    f32x4 acc = z4;
    bf16x8 awA[6], awB[6];

    // prologue
    LOADS(0);
    WRITES(0);
    LOADS(1);
    ALOAD(awA, 0);

    #pragma unroll
    for (int t = 0; t < 8; ++t) {
        const int buf = t & 1;
        // issue NEXT step's A-frag loads first (independent of this step's MFMAs)
        if (t < 7) {
            if (t & 1) ALOAD(awA, t + 1); else ALOAD(awB, t + 1);
        }
        // compute step t from buf, A-frags already in registers
        #pragma unroll
        for (int k = 0; k < 3; ++k) {
            const int row = lr + k;
            const char* rb = ldsW + buf * 2304 + row * 128;
            const int sw = (row & 7) << 4;
            #pragma unroll
            for (int kk = 0; kk < 2; ++kk) {
                bf16x8 kv = *(const bf16x8*)(rb + (((kk << 6) + (lk << 4)) ^ sw));
                bf16x8 a  = (t & 1) ? awB[k * 2 + kk] : awA[k * 2 + kk];
                acc = __builtin_amdgcn_mfma_f32_16x16x32_bf16(a, kv, acc, 0, 0, 0);
            }
        }
        if (t < 7) {
            WRITES(buf ^ 1);          // waits on key LOADS(t+1), converts, stores
            if (t < 6) LOADS(t + 2);  // in flight across next compute
        }
    }
    #undef LOADS
    #undef WRITES
    #undef ALOAD

    // combine d-halves (single barrier in whole kernel)
    if (dh == 1) {
        #pragma unroll
        for (int r4 = 0; r4 < 4; ++r4) red[ss][lk * 4 + r4][lr] = acc[r4];
    }
    __syncthreads();
    if (dh == 0) {
        const int s = sbase + lr;
        #pragma unroll
        for (int r4 = 0; r4 < 4; ++r4) {
            int h = lk * 4 + r4;
            out[(((b << 4) + h) << 10) + s] = acc[r4] + red[ss][h][lr];
        }
    }
}

extern "C" void kernel_launch(void* const* d_in, const int* in_sizes, int n_in,
                              void* d_out, int out_size, void* d_ws, size_t ws_size,
                              hipStream_t stream) {
    const float* Q  = (const float*)d_in[0];
    const float* K  = (const float*)d_in[1];
    const float* Wq = (const float*)d_in[4];
    const float* bq = (const float*)d_in[5];
    float* outp = (float*)d_out;

    short* wfrag = (short*)d_ws;                      // 98304 B
    short* wgtA  = (short*)((char*)d_ws + 98304);     // 3145728 B

    hipLaunchKernelGGL(prep_wfrag, dim3(192),  dim3(256), 0, stream, Wq, wfrag);
    hipLaunchKernelGGL(qk_gemm,    dim3(512),  dim3(256), 0, stream, Q, wfrag, bq, wgtA);
    hipLaunchKernelGGL(conv_mfma,  dim3(1024), dim3(256), 0, stream, K, wgtA, outp);
}